// Round 1
// baseline (3464.297 us; speedup 1.0000x reference)
//
#include <hip/hip_runtime.h>
#include <math.h>

#define B_    64
#define N_    128
#define S_    2048
#define D_    128
#define K_TOP 128

#define TN 64
#define TS 64
#define TK 32

// Monotone mapping: float total order -> unsigned total order
__device__ __forceinline__ unsigned fkey(float x) {
    unsigned u = __float_as_uint(x);
    return (u & 0x80000000u) ? ~u : (u | 0x80000000u);
}

// K1: scores[bz][n][s] = sum_k q[b,n,k]*d[b,s,k]   (NT GEMM, fp32 vector ALU)
__global__ __launch_bounds__(256) void gemm_scores(
    const float* __restrict__ q, const float* __restrict__ d,
    float* __restrict__ out, int b0)
{
    __shared__ float As[TN][TK + 1];   // +1 pad: stride 33 breaks pow2 bank aliasing
    __shared__ float Bs[TS][TK + 1];
    const int bz = blockIdx.z;
    const int b  = b0 + bz;
    const int n0 = blockIdx.y * TN;
    const int s0 = blockIdx.x * TS;
    const float* qb = q + (size_t)b * N_ * D_;
    const float* db = d + (size_t)b * S_ * D_;

    const int tx = threadIdx.x & 15;
    const int ty = threadIdx.x >> 4;

    float acc[4][4] = {};

    for (int k0 = 0; k0 < D_; k0 += TK) {
        // stage A (64x32) and B (64x32): 512 float4 each, 2 per thread
        for (int t = threadIdx.x; t < 512; t += 256) {
            int row = t >> 3;
            int c4  = (t & 7) << 2;
            float4 va = *(const float4*)(qb + (size_t)(n0 + row) * D_ + k0 + c4);
            As[row][c4 + 0] = va.x; As[row][c4 + 1] = va.y;
            As[row][c4 + 2] = va.z; As[row][c4 + 3] = va.w;
            float4 vb = *(const float4*)(db + (size_t)(s0 + row) * D_ + k0 + c4);
            Bs[row][c4 + 0] = vb.x; Bs[row][c4 + 1] = vb.y;
            Bs[row][c4 + 2] = vb.z; Bs[row][c4 + 3] = vb.w;
        }
        __syncthreads();
        #pragma unroll
        for (int kk = 0; kk < TK; ++kk) {
            float a0 = As[ty * 4 + 0][kk];
            float a1 = As[ty * 4 + 1][kk];
            float a2 = As[ty * 4 + 2][kk];
            float a3 = As[ty * 4 + 3][kk];
            float v0 = Bs[tx * 4 + 0][kk];
            float v1 = Bs[tx * 4 + 1][kk];
            float v2 = Bs[tx * 4 + 2][kk];
            float v3 = Bs[tx * 4 + 3][kk];
            acc[0][0] = fmaf(a0, v0, acc[0][0]); acc[0][1] = fmaf(a0, v1, acc[0][1]);
            acc[0][2] = fmaf(a0, v2, acc[0][2]); acc[0][3] = fmaf(a0, v3, acc[0][3]);
            acc[1][0] = fmaf(a1, v0, acc[1][0]); acc[1][1] = fmaf(a1, v1, acc[1][1]);
            acc[1][2] = fmaf(a1, v2, acc[1][2]); acc[1][3] = fmaf(a1, v3, acc[1][3]);
            acc[2][0] = fmaf(a2, v0, acc[2][0]); acc[2][1] = fmaf(a2, v1, acc[2][1]);
            acc[2][2] = fmaf(a2, v2, acc[2][2]); acc[2][3] = fmaf(a2, v3, acc[2][3]);
            acc[3][0] = fmaf(a3, v0, acc[3][0]); acc[3][1] = fmaf(a3, v1, acc[3][1]);
            acc[3][2] = fmaf(a3, v2, acc[3][2]); acc[3][3] = fmaf(a3, v3, acc[3][3]);
        }
        __syncthreads();
    }

    float* ob = out + ((size_t)bz * N_ + n0) * S_ + s0;
    #pragma unroll
    for (int i = 0; i < 4; ++i) {
        float4 v;
        v.x = acc[i][0]; v.y = acc[i][1]; v.z = acc[i][2]; v.w = acc[i][3];
        *(float4*)(ob + (size_t)(ty * 4 + i) * S_ + tx * 4) = v;
    }
}

// K2: exact radix-256 select of 128th-largest key per batch. One block per batch.
__global__ __launch_bounds__(256) void topk_select(
    const float* __restrict__ scores, unsigned* __restrict__ Tu, int b0)
{
    __shared__ unsigned hist[256 * 8];   // 8-way replicated to cut atomic serialization
    __shared__ unsigned bins[256];
    __shared__ unsigned sh_pref;
    __shared__ int sh_k;
    const int bz = blockIdx.x;
    const float* p = scores + (size_t)bz * N_ * S_;
    const int tid = threadIdx.x;
    const unsigned rep = tid & 7;
    if (tid == 0) { sh_pref = 0u; sh_k = K_TOP; }
    __syncthreads();

    for (int r = 0; r < 4; ++r) {
        for (int i = tid; i < 256 * 8; i += 256) hist[i] = 0u;
        __syncthreads();
        const unsigned pre = sh_pref;
        const int shift = 24 - 8 * r;
        const int hs = shift + 8;
        for (int i = tid; i < N_ * S_; i += 256) {
            unsigned u = fkey(p[i]);
            bool ok = (r == 0) || ((u >> hs) == (pre >> hs));
            if (ok) atomicAdd(&hist[(((u >> shift) & 255u) << 3) | rep], 1u);
        }
        __syncthreads();
        unsigned tot = 0;
        #pragma unroll
        for (int j = 0; j < 8; ++j) tot += hist[(tid << 3) | j];
        bins[tid] = tot;
        __syncthreads();
        if (tid == 0) {
            unsigned cum = 0; int kk = sh_k; unsigned sel = 0;
            for (int bin = 255; bin >= 0; --bin) {
                unsigned h = bins[bin];
                if (cum + h >= (unsigned)kk) { sel = (unsigned)bin; break; }
                cum += h;
            }
            sh_pref = pre | (sel << shift);
            sh_k = kk - (int)cum;
        }
        __syncthreads();
    }
    if (tid == 0) Tu[b0 + bz] = sh_pref;
}

// K3: per-batch rowmax sum + Z -> score.  One block (4 waves) per batch, wave per row.
__global__ __launch_bounds__(256) void row_score(
    const float* __restrict__ scores, const unsigned* __restrict__ Tu,
    float* __restrict__ outScore, int b0)
{
    const int bz = blockIdx.x;
    const int b  = b0 + bz;
    const unsigned T = Tu[b];
    const int lane = threadIdx.x & 63;
    const int w    = threadIdx.x >> 6;
    float sum = 0.f, cnt = 0.f;
    for (int n = w; n < N_; n += 4) {
        const float* p = scores + ((size_t)bz * N_ + n) * S_;
        float m = -INFINITY;
        for (int s = lane; s < S_; s += 64) {
            float x = p[s];
            if (fkey(x) >= T) m = fmaxf(m, x);
        }
        #pragma unroll
        for (int o = 32; o > 0; o >>= 1) m = fmaxf(m, __shfl_xor(m, o, 64));
        if (lane == 0 && m > -INFINITY) { sum += fmaxf(m, 0.f); cnt += 1.f; }
    }
    __shared__ float s_sum[4], s_cnt[4];
    if (lane == 0) { s_sum[w] = sum; s_cnt[w] = cnt; }
    __syncthreads();
    if (threadIdx.x == 0) {
        float Sv = s_sum[0] + s_sum[1] + s_sum[2] + s_sum[3];
        float Cv = s_cnt[0] + s_cnt[1] + s_cnt[2] + s_cnt[3];
        outScore[b] = Sv / fmaxf(Cv, 0.001f);
    }
}

// K4: loss = mean_b softplus(neg - pos)
__global__ __launch_bounds__(64) void final_loss(
    const float* __restrict__ sc, float* __restrict__ out)
{
    int b = threadIdx.x;
    float x = sc[B_ + b] - sc[b];
    float sp = (x > 20.f) ? x : log1pf(expf(x));
    #pragma unroll
    for (int o = 32; o > 0; o >>= 1) sp += __shfl_xor(sp, o, 64);
    if (b == 0) out[0] = sp * (1.f / B_);
}

extern "C" void kernel_launch(void* const* d_in, const int* in_sizes, int n_in,
                              void* d_out, int out_size, void* d_ws, size_t ws_size,
                              hipStream_t stream) {
    const float* q    = (const float*)d_in[0];
    const float* dpos = (const float*)d_in[1];
    const float* dneg = (const float*)d_in[2];
    float* out = (float*)d_out;
    char* ws = (char*)d_ws;

    const size_t per_batch = (size_t)N_ * S_ * sizeof(float);          // 1 MiB
    const size_t small = B_ * sizeof(unsigned) + 2 * B_ * sizeof(float);
    size_t avail = (ws_size > small) ? (ws_size - small) : 0;
    int Bc = (int)(avail / per_batch);
    if (Bc > B_) Bc = B_;
    if (Bc < 1) Bc = 1;

    float*    scores = (float*)ws;
    unsigned* Tu     = (unsigned*)(ws + per_batch * (size_t)Bc);
    float*    sc     = (float*)(ws + per_batch * (size_t)Bc + B_ * sizeof(unsigned));

    for (int c = 0; c < 2; ++c) {
        const float* docs = (c == 0) ? dpos : dneg;
        for (int b0 = 0; b0 < B_; b0 += Bc) {
            int nb = (B_ - b0 < Bc) ? (B_ - b0) : Bc;
            gemm_scores<<<dim3(S_ / TS, N_ / TN, nb), 256, 0, stream>>>(q, docs, scores, b0);
            topk_select<<<nb, 256, 0, stream>>>(scores, Tu, b0);
            row_score<<<nb, 256, 0, stream>>>(scores, Tu, sc + c * B_, b0);
        }
    }
    final_loss<<<1, 64, 0, stream>>>(sc, out);
}

// Round 2
// 1112.428 us; speedup vs baseline: 3.1142x; 3.1142x over previous
//
#include <hip/hip_runtime.h>
#include <math.h>

#define B_    64
#define N_    128
#define S_    2048
#define D_    128
#define K_TOP 128
#define CAP   4096

#define TN 64
#define TS 64
#define TK 32

// Monotone mapping: float total order -> unsigned total order
__device__ __forceinline__ unsigned fkey(float x) {
    unsigned u = __float_as_uint(x);
    return (u & 0x80000000u) ? ~u : (u | 0x80000000u);
}
__device__ __forceinline__ float unkey(unsigned k) {
    unsigned u = (k & 0x80000000u) ? (k & 0x7fffffffu) : ~k;
    return __uint_as_float(u);
}

// K0: zero per-chunk accumulators (hist, rowmaxKey, candCnt)
__global__ __launch_bounds__(256) void zero_ws(unsigned* __restrict__ p, int n) {
    int i = blockIdx.x * 256 + threadIdx.x;
    if (i < n) p[i] = 0u;
}

// K1: scores[bz][n][s] = q[b,n,:]·d[b,s,:]  + rowmax epilogue.
// Transposed LDS (As[k][n]) so inner-loop fragment reads are ds_read_b128.
__global__ __launch_bounds__(256) void gemm_scores(
    const float* __restrict__ q, const float* __restrict__ d,
    float* __restrict__ out, unsigned* __restrict__ rowmaxKey, int b0)
{
    __shared__ float As[TK][TN + 4];   // +4 pad keeps 16B alignment, skews banks
    __shared__ float Bs[TK][TS + 4];
    const int bz = blockIdx.z;
    const int b  = b0 + bz;
    const int n0 = blockIdx.y * TN;
    const int s0 = blockIdx.x * TS;
    const float* qb = q + (size_t)b * N_ * D_;
    const float* db = d + (size_t)b * S_ * D_;

    const int tx = threadIdx.x & 15;
    const int ty = threadIdx.x >> 4;

    float acc[4][4] = {};

    for (int k0 = 0; k0 < D_; k0 += TK) {
        for (int t = threadIdx.x; t < 512; t += 256) {
            int row = t >> 3;
            int c4  = (t & 7) << 2;
            float4 va = *(const float4*)(qb + (size_t)(n0 + row) * D_ + k0 + c4);
            As[c4 + 0][row] = va.x; As[c4 + 1][row] = va.y;
            As[c4 + 2][row] = va.z; As[c4 + 3][row] = va.w;
            float4 vb = *(const float4*)(db + (size_t)(s0 + row) * D_ + k0 + c4);
            Bs[c4 + 0][row] = vb.x; Bs[c4 + 1][row] = vb.y;
            Bs[c4 + 2][row] = vb.z; Bs[c4 + 3][row] = vb.w;
        }
        __syncthreads();
        #pragma unroll
        for (int kk = 0; kk < TK; ++kk) {
            float4 a = *(const float4*)&As[kk][ty * 4];
            float4 v = *(const float4*)&Bs[kk][tx * 4];
            acc[0][0] = fmaf(a.x, v.x, acc[0][0]); acc[0][1] = fmaf(a.x, v.y, acc[0][1]);
            acc[0][2] = fmaf(a.x, v.z, acc[0][2]); acc[0][3] = fmaf(a.x, v.w, acc[0][3]);
            acc[1][0] = fmaf(a.y, v.x, acc[1][0]); acc[1][1] = fmaf(a.y, v.y, acc[1][1]);
            acc[1][2] = fmaf(a.y, v.z, acc[1][2]); acc[1][3] = fmaf(a.y, v.w, acc[1][3]);
            acc[2][0] = fmaf(a.z, v.x, acc[2][0]); acc[2][1] = fmaf(a.z, v.y, acc[2][1]);
            acc[2][2] = fmaf(a.z, v.z, acc[2][2]); acc[2][3] = fmaf(a.z, v.w, acc[2][3]);
            acc[3][0] = fmaf(a.w, v.x, acc[3][0]); acc[3][1] = fmaf(a.w, v.y, acc[3][1]);
            acc[3][2] = fmaf(a.w, v.z, acc[3][2]); acc[3][3] = fmaf(a.w, v.w, acc[3][3]);
        }
        __syncthreads();
    }

    float* ob = out + ((size_t)bz * N_ + n0) * S_ + s0;
    #pragma unroll
    for (int i = 0; i < 4; ++i) {
        float4 v;
        v.x = acc[i][0]; v.y = acc[i][1]; v.z = acc[i][2]; v.w = acc[i][3];
        *(float4*)(ob + (size_t)(ty * 4 + i) * S_ + tx * 4) = v;
    }

    // rowmax epilogue: 16 threads (tx) share each of the 64 rows
    #pragma unroll
    for (int i = 0; i < 4; ++i) {
        unsigned km = fkey(acc[i][0]);
        km = max(km, fkey(acc[i][1]));
        km = max(km, fkey(acc[i][2]));
        km = max(km, fkey(acc[i][3]));
        #pragma unroll
        for (int off = 1; off < 16; off <<= 1)
            km = max(km, (unsigned)__shfl_xor((int)km, off, 16));
        if (tx == 0)
            atomicMax(&rowmaxKey[bz * N_ + n0 + ty * 4 + i], km);
    }
}

// K2: per-batch 2048-bin histogram of top-11-bit keys. 8 blocks/batch, 4-way LDS replicas.
__global__ __launch_bounds__(256) void hist_kernel(
    const float* __restrict__ scores, unsigned* __restrict__ ghist)
{
    __shared__ unsigned hl[2048 * 4];
    const int bz  = blockIdx.x >> 3;
    const int seg = blockIdx.x & 7;
    const int tid = threadIdx.x;
    for (int i = tid; i < 2048 * 4; i += 256) hl[i] = 0u;
    __syncthreads();
    const float4* p = (const float4*)(scores + (size_t)bz * N_ * S_) + (size_t)seg * 8192;
    const unsigned rep = tid & 3;
    for (int i = tid; i < 8192; i += 256) {
        float4 v = p[i];
        atomicAdd(&hl[((fkey(v.x) >> 21) << 2) | rep], 1u);
        atomicAdd(&hl[((fkey(v.y) >> 21) << 2) | rep], 1u);
        atomicAdd(&hl[((fkey(v.z) >> 21) << 2) | rep], 1u);
        atomicAdd(&hl[((fkey(v.w) >> 21) << 2) | rep], 1u);
    }
    __syncthreads();
    for (int i = tid; i < 2048; i += 256) {
        unsigned s = hl[i * 4] + hl[i * 4 + 1] + hl[i * 4 + 2] + hl[i * 4 + 3];
        if (s) atomicAdd(&ghist[bz * 2048 + i], s);
    }
}

// K3: per-batch scan: which bin holds the 128th-largest; how many lie strictly above it.
__global__ __launch_bounds__(256) void find_bin(
    const unsigned* __restrict__ ghist, unsigned* __restrict__ binIdx,
    unsigned* __restrict__ kRem)
{
    __shared__ unsigned bins[2048];
    const int bz = blockIdx.x;
    for (int i = threadIdx.x; i < 2048; i += 256) bins[i] = ghist[bz * 2048 + i];
    __syncthreads();
    if (threadIdx.x == 0) {
        unsigned cum = 0;
        for (int bin = 2047; bin >= 0; --bin) {
            unsigned h = bins[bin];
            if (cum + h >= K_TOP) { binIdx[bz] = (unsigned)bin; kRem[bz] = K_TOP - cum; break; }
            cum += h;
        }
    }
}

// K4: gather keys falling in the cutoff bin (expected ~600/batch)
__global__ __launch_bounds__(256) void collect(
    const float* __restrict__ scores, const unsigned* __restrict__ binIdx,
    unsigned* __restrict__ cand, unsigned* __restrict__ candCnt, int nb)
{
    const int total4 = nb * (N_ * S_ / 4);       // N*S/4 = 65536 per batch
    const int stride = gridDim.x * 256;
    for (int idx = blockIdx.x * 256 + threadIdx.x; idx < total4; idx += stride) {
        int b = idx >> 16;
        unsigned bi = binIdx[b];
        float4 v = ((const float4*)scores)[idx];
        unsigned u;
        u = fkey(v.x); if ((u >> 21) == bi) { unsigned p = atomicAdd(&candCnt[b], 1u); if (p < CAP) cand[(size_t)b * CAP + p] = u; }
        u = fkey(v.y); if ((u >> 21) == bi) { unsigned p = atomicAdd(&candCnt[b], 1u); if (p < CAP) cand[(size_t)b * CAP + p] = u; }
        u = fkey(v.z); if ((u >> 21) == bi) { unsigned p = atomicAdd(&candCnt[b], 1u); if (p < CAP) cand[(size_t)b * CAP + p] = u; }
        u = fkey(v.w); if ((u >> 21) == bi) { unsigned p = atomicAdd(&candCnt[b], 1u); if (p < CAP) cand[(size_t)b * CAP + p] = u; }
    }
}

// K5: exact select of the kRem-th largest among candidates (radix over low 21 bits)
__global__ __launch_bounds__(256) void exact_select(
    const unsigned* __restrict__ cand, const unsigned* __restrict__ candCnt,
    const unsigned* __restrict__ binIdx, const unsigned* __restrict__ kRem,
    unsigned* __restrict__ Tkey)
{
    __shared__ unsigned list[CAP];
    __shared__ unsigned h[128];
    __shared__ unsigned sh_pref;
    __shared__ int sh_k;
    const int bz  = blockIdx.x;
    const int tid = threadIdx.x;
    int cnt = (int)min(candCnt[bz], (unsigned)CAP);
    for (int i = tid; i < cnt; i += 256) list[i] = cand[(size_t)bz * CAP + i];
    if (tid == 0) { sh_pref = 0u; sh_k = (int)kRem[bz]; }
    __syncthreads();

    #pragma unroll
    for (int r = 0; r < 3; ++r) {
        const int shift = 14 - 7 * r;
        for (int i = tid; i < 128; i += 256) h[i] = 0u;
        __syncthreads();
        const unsigned pref = sh_pref;
        for (int i = tid; i < cnt; i += 256) {
            unsigned u = list[i] & 0x1FFFFFu;
            if ((u >> (shift + 7)) == pref) atomicAdd(&h[(u >> shift) & 127u], 1u);
        }
        __syncthreads();
        if (tid == 0) {
            unsigned cum = 0;
            for (int v = 127; v >= 0; --v) {
                unsigned hh = h[v];
                if (cum + hh >= (unsigned)sh_k) { sh_pref = (pref << 7) | (unsigned)v; sh_k -= (int)cum; break; }
                cum += hh;
            }
        }
        __syncthreads();
    }
    if (tid == 0) Tkey[bz] = (binIdx[bz] << 21) | sh_pref;
}

// K6: per-batch score from 128 rowmax keys
__global__ __launch_bounds__(128) void batch_score(
    const unsigned* __restrict__ rowmaxKey, const unsigned* __restrict__ Tkey,
    float* __restrict__ sc, int b0)
{
    __shared__ float s_sum[2], s_cnt[2];
    const int bz = blockIdx.x;
    const unsigned T = Tkey[bz];
    const int n = threadIdx.x;
    unsigned km = rowmaxKey[bz * N_ + n];
    bool inc = (km >= T);
    float v = inc ? fmaxf(unkey(km), 0.f) : 0.f;
    float c = inc ? 1.f : 0.f;
    #pragma unroll
    for (int off = 32; off > 0; off >>= 1) {
        v += __shfl_xor(v, off, 64);
        c += __shfl_xor(c, off, 64);
    }
    const int w = n >> 6;
    if ((n & 63) == 0) { s_sum[w] = v; s_cnt[w] = c; }
    __syncthreads();
    if (n == 0) {
        float Sv = s_sum[0] + s_sum[1];
        float Cv = s_cnt[0] + s_cnt[1];
        sc[b0 + bz] = Sv / fmaxf(Cv, 0.001f);
    }
}

// K7: loss = mean_b softplus(neg - pos)
__global__ __launch_bounds__(64) void final_loss(
    const float* __restrict__ sc, float* __restrict__ out)
{
    int b = threadIdx.x;
    float x = sc[B_ + b] - sc[b];
    float sp = (x > 20.f) ? x : log1pf(expf(x));
    #pragma unroll
    for (int o = 32; o > 0; o >>= 1) sp += __shfl_xor(sp, o, 64);
    if (b == 0) out[0] = sp * (1.f / B_);
}

extern "C" void kernel_launch(void* const* d_in, const int* in_sizes, int n_in,
                              void* d_out, int out_size, void* d_ws, size_t ws_size,
                              hipStream_t stream) {
    const float* q    = (const float*)d_in[0];
    const float* dpos = (const float*)d_in[1];
    const float* dneg = (const float*)d_in[2];
    float* out = (float*)d_out;
    char* ws = (char*)d_ws;

    // bytes per batch in the chunked region
    const size_t per_batch = (size_t)N_ * S_ * 4   // scores
                           + 2048 * 4              // hist
                           + N_ * 4                // rowmaxKey
                           + (size_t)CAP * 4       // cand
                           + 4 + 4 + 4 + 4;        // candCnt, binIdx, kRem, Tkey
    const size_t fixed = 2 * B_ * sizeof(float);   // sc
    size_t avail = (ws_size > fixed + 64) ? (ws_size - fixed - 64) : 0;
    int Bc = (int)(avail / per_batch);
    if (Bc > B_) Bc = B_;
    if (Bc < 1) Bc = 1;

    char* p = ws;
    float* sc = (float*)p; p += ((fixed + 63) / 64) * 64;   // keep 16B alignment after
    float*    scores  = (float*)p;    p += (size_t)Bc * N_ * S_ * 4;
    unsigned* ghist   = (unsigned*)p; p += (size_t)Bc * 2048 * 4;
    unsigned* cand    = (unsigned*)p; p += (size_t)Bc * CAP * 4;
    unsigned* rowmax  = (unsigned*)p; p += (size_t)Bc * N_ * 4;
    unsigned* candCnt = (unsigned*)p; p += (size_t)Bc * 4;
    unsigned* binIdx  = (unsigned*)p; p += (size_t)Bc * 4;
    unsigned* kRem    = (unsigned*)p; p += (size_t)Bc * 4;
    unsigned* Tkey    = (unsigned*)p; p += (size_t)Bc * 4;

    for (int c = 0; c < 2; ++c) {
        const float* docs = (c == 0) ? dpos : dneg;
        for (int b0 = 0; b0 < B_; b0 += Bc) {
            int nb = (B_ - b0 < Bc) ? (B_ - b0) : Bc;
            // zero ghist (nb*2048) + rowmax (nb*128) + candCnt (nb)
            {
                int zw = nb * 2048;
                zero_ws<<<(zw + 255) / 256, 256, 0, stream>>>(ghist, zw);
                zw = nb * N_;
                zero_ws<<<(zw + 255) / 256, 256, 0, stream>>>(rowmax, zw);
                zero_ws<<<(nb + 255) / 256, 256, 0, stream>>>(candCnt, nb);
            }
            gemm_scores<<<dim3(S_ / TS, N_ / TN, nb), 256, 0, stream>>>(q, docs, scores, rowmax, b0);
            hist_kernel<<<nb * 8, 256, 0, stream>>>(scores, ghist);
            find_bin<<<nb, 256, 0, stream>>>(ghist, binIdx, kRem);
            collect<<<1024, 256, 0, stream>>>(scores, binIdx, cand, candCnt, nb);
            exact_select<<<nb, 256, 0, stream>>>(cand, candCnt, binIdx, kRem, Tkey);
            batch_score<<<nb, 128, 0, stream>>>(rowmax, Tkey, sc + c * B_, b0);
        }
    }
    final_loss<<<1, 64, 0, stream>>>(sc, out);
}

// Round 3
// 376.004 us; speedup vs baseline: 9.2134x; 2.9585x over previous
//
#include <hip/hip_runtime.h>
#include <math.h>

#define B_    64
#define N_    128
#define S_    2048
#define D_    128
#define K_TOP 128
#define CAP   4096

#define TN 64
#define TS 64
#define TK 32

// Monotone mapping: float total order -> unsigned total order
__device__ __forceinline__ unsigned fkey(float x) {
    unsigned u = __float_as_uint(x);
    return (u & 0x80000000u) ? ~u : (u | 0x80000000u);
}
__device__ __forceinline__ float unkey(unsigned k) {
    unsigned u = (k & 0x80000000u) ? (k & 0x7fffffffu) : ~k;
    return __uint_as_float(u);
}

// K0: zero the per-chunk accumulator region (ghist|rowmax|candCnt, contiguous)
__global__ __launch_bounds__(256) void zero_ws(unsigned* __restrict__ p, int n) {
    int i = blockIdx.x * 256 + threadIdx.x;
    if (i < n) p[i] = 0u;
}

// K1: scores[bz][n][s] = q[b,n,:]·d[b,s,:]  + rowmax epilogue.
__global__ __launch_bounds__(256) void gemm_scores(
    const float* __restrict__ q, const float* __restrict__ d,
    float* __restrict__ out, unsigned* __restrict__ rowmaxKey, int b0)
{
    __shared__ float As[TK][TN + 4];
    __shared__ float Bs[TK][TS + 4];
    const int bz = blockIdx.z;
    const int b  = b0 + bz;
    const int n0 = blockIdx.y * TN;
    const int s0 = blockIdx.x * TS;
    const float* qb = q + (size_t)b * N_ * D_;
    const float* db = d + (size_t)b * S_ * D_;

    const int tx = threadIdx.x & 15;
    const int ty = threadIdx.x >> 4;

    float acc[4][4] = {};

    for (int k0 = 0; k0 < D_; k0 += TK) {
        for (int t = threadIdx.x; t < 512; t += 256) {
            int row = t >> 3;
            int c4  = (t & 7) << 2;
            float4 va = *(const float4*)(qb + (size_t)(n0 + row) * D_ + k0 + c4);
            As[c4 + 0][row] = va.x; As[c4 + 1][row] = va.y;
            As[c4 + 2][row] = va.z; As[c4 + 3][row] = va.w;
            float4 vb = *(const float4*)(db + (size_t)(s0 + row) * D_ + k0 + c4);
            Bs[c4 + 0][row] = vb.x; Bs[c4 + 1][row] = vb.y;
            Bs[c4 + 2][row] = vb.z; Bs[c4 + 3][row] = vb.w;
        }
        __syncthreads();
        #pragma unroll
        for (int kk = 0; kk < TK; ++kk) {
            float4 a = *(const float4*)&As[kk][ty * 4];
            float4 v = *(const float4*)&Bs[kk][tx * 4];
            acc[0][0] = fmaf(a.x, v.x, acc[0][0]); acc[0][1] = fmaf(a.x, v.y, acc[0][1]);
            acc[0][2] = fmaf(a.x, v.z, acc[0][2]); acc[0][3] = fmaf(a.x, v.w, acc[0][3]);
            acc[1][0] = fmaf(a.y, v.x, acc[1][0]); acc[1][1] = fmaf(a.y, v.y, acc[1][1]);
            acc[1][2] = fmaf(a.y, v.z, acc[1][2]); acc[1][3] = fmaf(a.y, v.w, acc[1][3]);
            acc[2][0] = fmaf(a.z, v.x, acc[2][0]); acc[2][1] = fmaf(a.z, v.y, acc[2][1]);
            acc[2][2] = fmaf(a.z, v.z, acc[2][2]); acc[2][3] = fmaf(a.z, v.w, acc[2][3]);
            acc[3][0] = fmaf(a.w, v.x, acc[3][0]); acc[3][1] = fmaf(a.w, v.y, acc[3][1]);
            acc[3][2] = fmaf(a.w, v.z, acc[3][2]); acc[3][3] = fmaf(a.w, v.w, acc[3][3]);
        }
        __syncthreads();
    }

    float* ob = out + ((size_t)bz * N_ + n0) * S_ + s0;
    #pragma unroll
    for (int i = 0; i < 4; ++i) {
        float4 v;
        v.x = acc[i][0]; v.y = acc[i][1]; v.z = acc[i][2]; v.w = acc[i][3];
        *(float4*)(ob + (size_t)(ty * 4 + i) * S_ + tx * 4) = v;
    }

    #pragma unroll
    for (int i = 0; i < 4; ++i) {
        unsigned km = fkey(acc[i][0]);
        km = max(km, fkey(acc[i][1]));
        km = max(km, fkey(acc[i][2]));
        km = max(km, fkey(acc[i][3]));
        #pragma unroll
        for (int off = 1; off < 16; off <<= 1)
            km = max(km, (unsigned)__shfl_xor((int)km, off, 16));
        if (tx == 0)
            atomicMax(&rowmaxKey[bz * N_ + n0 + ty * 4 + i], km);
    }
}

// K2: per-batch 2048-bin histogram of top-11-bit keys. 8 blocks/batch, 4-way LDS replicas.
__global__ __launch_bounds__(256) void hist_kernel(
    const float* __restrict__ scores, unsigned* __restrict__ ghist)
{
    __shared__ unsigned hl[2048 * 4];
    const int bz  = blockIdx.x >> 3;
    const int seg = blockIdx.x & 7;
    const int tid = threadIdx.x;
    for (int i = tid; i < 2048 * 4; i += 256) hl[i] = 0u;
    __syncthreads();
    const float4* p = (const float4*)(scores + (size_t)bz * N_ * S_) + (size_t)seg * 8192;
    const unsigned rep = tid & 3;
    for (int i = tid; i < 8192; i += 256) {
        float4 v = p[i];
        atomicAdd(&hl[((fkey(v.x) >> 21) << 2) | rep], 1u);
        atomicAdd(&hl[((fkey(v.y) >> 21) << 2) | rep], 1u);
        atomicAdd(&hl[((fkey(v.z) >> 21) << 2) | rep], 1u);
        atomicAdd(&hl[((fkey(v.w) >> 21) << 2) | rep], 1u);
    }
    __syncthreads();
    for (int i = tid; i < 2048; i += 256) {
        unsigned s = hl[i * 4] + hl[i * 4 + 1] + hl[i * 4 + 2] + hl[i * 4 + 3];
        if (s) atomicAdd(&ghist[bz * 2048 + i], s);
    }
}

// K3: per-batch scan for cutoff bin. Parallel: 256 threads x 8 bins each.
__global__ __launch_bounds__(256) void find_bin(
    const unsigned* __restrict__ ghist, unsigned* __restrict__ binIdx,
    unsigned* __restrict__ kRem)
{
    __shared__ unsigned bins[2048];
    __shared__ unsigned csum[256];
    const int bz  = blockIdx.x;
    const int tid = threadIdx.x;
    for (int i = tid; i < 2048; i += 256) bins[i] = ghist[bz * 2048 + i];
    __syncthreads();
    // chunk t covers bins [t*8, t*8+8); csum[t] = total in chunk
    unsigned s = 0;
    #pragma unroll
    for (int j = 0; j < 8; ++j) s += bins[tid * 8 + j];
    csum[tid] = s;
    __syncthreads();
    if (tid == 0) {
        unsigned cum = 0;
        int t;
        for (t = 255; t >= 0; --t) {               // find chunk from top
            if (cum + csum[t] >= K_TOP) break;
            cum += csum[t];
        }
        for (int bin = t * 8 + 7; bin >= t * 8; --bin) {
            unsigned h = bins[bin];
            if (cum + h >= K_TOP) { binIdx[bz] = (unsigned)bin; kRem[bz] = K_TOP - cum; break; }
            cum += h;
        }
    }
}

// K4: gather cutoff-bin keys. Block-contiguous segments (16/batch), LDS compaction,
// one global atomic per block.
__global__ __launch_bounds__(256) void collect(
    const float* __restrict__ scores, const unsigned* __restrict__ binIdx,
    unsigned* __restrict__ cand, unsigned* __restrict__ candCnt)
{
    __shared__ unsigned buf[CAP];
    __shared__ unsigned lcnt;
    __shared__ unsigned gbase;
    const int bz  = blockIdx.x >> 4;
    const int seg = blockIdx.x & 15;
    const int tid = threadIdx.x;
    if (tid == 0) lcnt = 0u;
    __syncthreads();
    const unsigned bi = binIdx[bz];
    const float4* p = (const float4*)(scores + (size_t)bz * N_ * S_) + (size_t)seg * 4096;
    for (int i = tid; i < 4096; i += 256) {
        float4 v = p[i];
        unsigned u;
        u = fkey(v.x); if ((u >> 21) == bi) { unsigned q = atomicAdd(&lcnt, 1u); if (q < CAP) buf[q] = u; }
        u = fkey(v.y); if ((u >> 21) == bi) { unsigned q = atomicAdd(&lcnt, 1u); if (q < CAP) buf[q] = u; }
        u = fkey(v.z); if ((u >> 21) == bi) { unsigned q = atomicAdd(&lcnt, 1u); if (q < CAP) buf[q] = u; }
        u = fkey(v.w); if ((u >> 21) == bi) { unsigned q = atomicAdd(&lcnt, 1u); if (q < CAP) buf[q] = u; }
    }
    __syncthreads();
    unsigned c = min(lcnt, (unsigned)CAP);
    if (tid == 0 && c) gbase = atomicAdd(&candCnt[bz], c);
    __syncthreads();
    for (unsigned i = tid; i < c; i += 256) {
        unsigned pos = gbase + i;
        if (pos < CAP) cand[(size_t)bz * CAP + pos] = buf[i];
    }
}

// K5: exact select of the kRem-th largest among candidates (radix over low 21 bits)
__global__ __launch_bounds__(256) void exact_select(
    const unsigned* __restrict__ cand, const unsigned* __restrict__ candCnt,
    const unsigned* __restrict__ binIdx, const unsigned* __restrict__ kRem,
    unsigned* __restrict__ Tkey)
{
    __shared__ unsigned list[CAP];
    __shared__ unsigned h[128];
    __shared__ unsigned sh_pref;
    __shared__ int sh_k;
    const int bz  = blockIdx.x;
    const int tid = threadIdx.x;
    int cnt = (int)min(candCnt[bz], (unsigned)CAP);
    for (int i = tid; i < cnt; i += 256) list[i] = cand[(size_t)bz * CAP + i];
    if (tid == 0) { sh_pref = 0u; sh_k = (int)kRem[bz]; }
    __syncthreads();

    #pragma unroll
    for (int r = 0; r < 3; ++r) {
        const int shift = 14 - 7 * r;
        for (int i = tid; i < 128; i += 256) h[i] = 0u;
        __syncthreads();
        const unsigned pref = sh_pref;
        for (int i = tid; i < cnt; i += 256) {
            unsigned u = list[i] & 0x1FFFFFu;
            if ((u >> (shift + 7)) == pref) atomicAdd(&h[(u >> shift) & 127u], 1u);
        }
        __syncthreads();
        if (tid == 0) {
            unsigned cum = 0;
            for (int v = 127; v >= 0; --v) {
                unsigned hh = h[v];
                if (cum + hh >= (unsigned)sh_k) { sh_pref = (pref << 7) | (unsigned)v; sh_k -= (int)cum; break; }
                cum += hh;
            }
        }
        __syncthreads();
    }
    if (tid == 0) Tkey[bz] = (binIdx[bz] << 21) | sh_pref;
}

// K6: per-batch score from 128 rowmax keys
__global__ __launch_bounds__(128) void batch_score(
    const unsigned* __restrict__ rowmaxKey, const unsigned* __restrict__ Tkey,
    float* __restrict__ sc, int b0)
{
    __shared__ float s_sum[2], s_cnt[2];
    const int bz = blockIdx.x;
    const unsigned T = Tkey[bz];
    const int n = threadIdx.x;
    unsigned km = rowmaxKey[bz * N_ + n];
    bool inc = (km >= T);
    float v = inc ? fmaxf(unkey(km), 0.f) : 0.f;
    float c = inc ? 1.f : 0.f;
    #pragma unroll
    for (int off = 32; off > 0; off >>= 1) {
        v += __shfl_xor(v, off, 64);
        c += __shfl_xor(c, off, 64);
    }
    const int w = n >> 6;
    if ((n & 63) == 0) { s_sum[w] = v; s_cnt[w] = c; }
    __syncthreads();
    if (n == 0) {
        float Sv = s_sum[0] + s_sum[1];
        float Cv = s_cnt[0] + s_cnt[1];
        sc[b0 + bz] = Sv / fmaxf(Cv, 0.001f);
    }
}

// K7: loss = mean_b softplus(neg - pos)
__global__ __launch_bounds__(64) void final_loss(
    const float* __restrict__ sc, float* __restrict__ out)
{
    int b = threadIdx.x;
    float x = sc[B_ + b] - sc[b];
    float sp = (x > 20.f) ? x : log1pf(expf(x));
    #pragma unroll
    for (int o = 32; o > 0; o >>= 1) sp += __shfl_xor(sp, o, 64);
    if (b == 0) out[0] = sp * (1.f / B_);
}

extern "C" void kernel_launch(void* const* d_in, const int* in_sizes, int n_in,
                              void* d_out, int out_size, void* d_ws, size_t ws_size,
                              hipStream_t stream) {
    const float* q    = (const float*)d_in[0];
    const float* dpos = (const float*)d_in[1];
    const float* dneg = (const float*)d_in[2];
    float* out = (float*)d_out;
    char* ws = (char*)d_ws;

    // per-batch bytes: scores + zero-region (ghist+rowmax+candCnt) + cand + 3 scalars
    const size_t per_batch = (size_t)N_ * S_ * 4
                           + (2048 + N_ + 1) * 4
                           + (size_t)CAP * 4
                           + 12;
    const size_t fixed = 2 * B_ * sizeof(float) + 4096;  // sc + alignment slack
    size_t avail = (ws_size > fixed) ? (ws_size - fixed) : 0;
    int Bc = (int)(avail / per_batch);
    if (Bc > B_) Bc = B_;
    if (Bc < 1) Bc = 1;

    const int zwords = Bc * (2048 + N_ + 1);             // contiguous zero region

    char* p = ws;
    float*    sc      = (float*)p; p += ((2 * B_ * 4 + 63) / 64) * 64;
    unsigned* ghist   = (unsigned*)p;                     // zero region start
    unsigned* rowmax  = ghist + (size_t)Bc * 2048;
    unsigned* candCnt = rowmax + (size_t)Bc * N_;
    p += ((size_t)zwords * 4 + 63) / 64 * 64;
    float*    scores  = (float*)p;    p += (size_t)Bc * N_ * S_ * 4;
    unsigned* cand    = (unsigned*)p; p += (size_t)Bc * CAP * 4;
    unsigned* binIdx  = (unsigned*)p; p += (size_t)Bc * 4;
    unsigned* kRem    = (unsigned*)p; p += (size_t)Bc * 4;
    unsigned* Tkey    = (unsigned*)p; p += (size_t)Bc * 4;

    for (int c = 0; c < 2; ++c) {
        const float* docs = (c == 0) ? dpos : dneg;
        for (int b0 = 0; b0 < B_; b0 += Bc) {
            int nb = (B_ - b0 < Bc) ? (B_ - b0) : Bc;
            int zw = nb * 2048;   // ghist part for nb batches
            // zero ghist[0:nb*2048] and rowmax/candCnt: they are contiguous only
            // when nb == Bc; zero the full Bc-sized region (cheap) to be safe.
            zero_ws<<<(zwords + 255) / 256, 256, 0, stream>>>(ghist, zwords);
            (void)zw;
            gemm_scores<<<dim3(S_ / TS, N_ / TN, nb), 256, 0, stream>>>(q, docs, scores, rowmax, b0);
            hist_kernel<<<nb * 8, 256, 0, stream>>>(scores, ghist);
            find_bin<<<nb, 256, 0, stream>>>(ghist, binIdx, kRem);
            collect<<<nb * 16, 256, 0, stream>>>(scores, binIdx, cand, candCnt);
            exact_select<<<nb, 256, 0, stream>>>(cand, candCnt, binIdx, kRem, Tkey);
            batch_score<<<nb, 128, 0, stream>>>(rowmax, Tkey, sc + c * B_, b0);
        }
    }
    final_loss<<<1, 64, 0, stream>>>(sc, out);
}

// Round 4
// 300.480 us; speedup vs baseline: 11.5292x; 1.2513x over previous
//
#include <hip/hip_runtime.h>
#include <math.h>

#define B_    64
#define N_    128
#define S_    2048
#define D_    128
#define K_TOP 128
#define CAP   4096

typedef __bf16 bf16x8 __attribute__((ext_vector_type(8)));
typedef float  f32x4  __attribute__((ext_vector_type(4)));

union Frag { uint4 u; bf16x8 b; };

// Monotone mapping: float total order -> unsigned total order
__device__ __forceinline__ unsigned fkey(float x) {
    unsigned u = __float_as_uint(x);
    return (u & 0x80000000u) ? ~u : (u | 0x80000000u);
}
__device__ __forceinline__ float unkey(unsigned k) {
    unsigned u = (k & 0x80000000u) ? (k & 0x7fffffffu) : ~k;
    return __uint_as_float(u);
}

// 8 fp32 -> 8 bf16 hi (truncate) + 8 bf16 lo (exact residual, truncate)
__device__ __forceinline__ void cvt8(float4 a, float4 b, uint4& hi, uint4& lo) {
    float v[8] = {a.x, a.y, a.z, a.w, b.x, b.y, b.z, b.w};
    unsigned h[8], l[8];
    #pragma unroll
    for (int i = 0; i < 8; ++i) {
        unsigned u = __float_as_uint(v[i]);
        h[i] = u >> 16;
        float fh = __uint_as_float(u & 0xFFFF0000u);
        l[i] = __float_as_uint(v[i] - fh) >> 16;   // v - hi is exact in fp32
    }
    hi.x = h[0] | (h[1] << 16); hi.y = h[2] | (h[3] << 16);
    hi.z = h[4] | (h[5] << 16); hi.w = h[6] | (h[7] << 16);
    lo.x = l[0] | (l[1] << 16); lo.y = l[2] | (l[3] << 16);
    lo.z = l[4] | (l[5] << 16); lo.w = l[6] | (l[7] << 16);
}

// K0: zero per-chunk accumulators (ghist|rowmax|candCnt contiguous)
__global__ __launch_bounds__(256) void zero_ws(unsigned* __restrict__ p, int n) {
    int i = blockIdx.x * 256 + threadIdx.x;
    if (i < n) p[i] = 0u;
}

// K1: split-bf16 MFMA GEMM (hi*hi + hi*lo + lo*hi), 128x128 tile, K=128.
// Epilogues: score store, per-row max (atomicMax), 2048-bin key histogram.
// LDS tiles are fragment-major: chunk ci = I*64 + (quad*16+m) holds
// row (I*16+m), k (k0 + quad*8 .. +7) as 8 bf16 -> frag reads and staging
// writes are both lane-consecutive ds_*_b128 (conflict-free).
__global__ __launch_bounds__(256) void gemm_fused(
    const float* __restrict__ q, const float* __restrict__ d,
    float* __restrict__ scores, unsigned* __restrict__ rowmaxKey,
    unsigned* __restrict__ ghist, int b0)
{
    __shared__ uint4 sh4[2048];   // A_hi[512] | A_lo[512] | B_hi[512] | B_lo[512]
    const int bz = blockIdx.z;
    const int s0 = blockIdx.x * 128;
    const float* qb = q + (size_t)(b0 + bz) * N_ * D_;
    const float* db = d + (size_t)(b0 + bz) * S_ * D_;

    const int t    = threadIdx.x;
    const int lane = t & 63;
    const int w    = t >> 6;
    const int quad = lane >> 4;
    const int m    = lane & 15;

    f32x4 acc[4][4];
    #pragma unroll
    for (int i = 0; i < 4; ++i)
        #pragma unroll
        for (int j = 0; j < 4; ++j)
            acc[i][j] = f32x4{0.f, 0.f, 0.f, 0.f};

    for (int k0 = 0; k0 < D_; k0 += 32) {
        #pragma unroll
        for (int p = 0; p < 2; ++p) {
            int c   = t + p * 256;                     // chunk 0..511
            int row = ((c >> 6) << 4) | (c & 15);      // I*16 + m
            int kk  = k0 + (((c >> 4) & 3) << 3);      // quad*8
            const float* ga = qb + (size_t)row * D_ + kk;
            float4 a0 = *(const float4*)ga;
            float4 a1 = *(const float4*)(ga + 4);
            uint4 hi, lo;
            cvt8(a0, a1, hi, lo);
            sh4[c] = hi; sh4[512 + c] = lo;
            const float* gb = db + (size_t)(s0 + row) * D_ + kk;
            float4 b0v = *(const float4*)gb;
            float4 b1v = *(const float4*)(gb + 4);
            cvt8(b0v, b1v, hi, lo);
            sh4[1024 + c] = hi; sh4[1536 + c] = lo;
        }
        __syncthreads();

        Frag ah[4], al[4], bh[4], bl[4];
        #pragma unroll
        for (int i = 0; i < 4; ++i) {
            int I = ((w >> 1) << 2) + i;               // row-subtile 0..7
            ah[i].u = sh4[I * 64 + lane];
            al[i].u = sh4[512 + I * 64 + lane];
            int J = ((w & 1) << 2) + i;                // col-subtile 0..7
            bh[i].u = sh4[1024 + J * 64 + lane];
            bl[i].u = sh4[1536 + J * 64 + lane];
        }
        #pragma unroll
        for (int i = 0; i < 4; ++i)
            #pragma unroll
            for (int j = 0; j < 4; ++j) {
                acc[i][j] = __builtin_amdgcn_mfma_f32_16x16x32_bf16(ah[i].b, bh[j].b, acc[i][j], 0, 0, 0);
                acc[i][j] = __builtin_amdgcn_mfma_f32_16x16x32_bf16(ah[i].b, bl[j].b, acc[i][j], 0, 0, 0);
                acc[i][j] = __builtin_amdgcn_mfma_f32_16x16x32_bf16(al[i].b, bh[j].b, acc[i][j], 0, 0, 0);
            }
        __syncthreads();
    }

    // Epilogue 1: store scores + per-row max.
    // C/D layout (m89-verified): col = lane&15, row = quad*4 + reg.
    float* sb = scores + (size_t)bz * N_ * S_ + s0;
    #pragma unroll
    for (int i = 0; i < 4; ++i) {
        int I = ((w >> 1) << 2) + i;
        #pragma unroll
        for (int r = 0; r < 4; ++r) {
            int row = (I << 4) + (quad << 2) + r;
            unsigned km = 0u;
            #pragma unroll
            for (int j = 0; j < 4; ++j) {
                int J = ((w & 1) << 2) + j;
                float v = acc[i][j][r];
                sb[(size_t)row * S_ + (J << 4) + m] = v;
                km = max(km, fkey(v));
            }
            #pragma unroll
            for (int off = 1; off < 16; off <<= 1)
                km = max(km, (unsigned)__shfl_xor((int)km, off, 64));
            if (m == 0) atomicMax(&rowmaxKey[bz * N_ + row], km);
        }
    }

    // Epilogue 2: 2048-bin histogram of key>>21, 4-way replicated in reused LDS.
    __syncthreads();
    unsigned* shist = (unsigned*)sh4;                 // 2048 bins x 4 replicas
    for (int i = t; i < 2048 * 4; i += 256) shist[i] = 0u;
    __syncthreads();
    const unsigned rep = t & 3;
    #pragma unroll
    for (int i = 0; i < 4; ++i)
        #pragma unroll
        for (int j = 0; j < 4; ++j)
            #pragma unroll
            for (int r = 0; r < 4; ++r)
                atomicAdd(&shist[((fkey(acc[i][j][r]) >> 21) << 2) | rep], 1u);
    __syncthreads();
    for (int i = t; i < 2048; i += 256) {
        unsigned c = shist[i * 4] + shist[i * 4 + 1] + shist[i * 4 + 2] + shist[i * 4 + 3];
        if (c) atomicAdd(&ghist[bz * 2048 + i], c);
    }
}

// K3: per-batch scan for cutoff bin.
__global__ __launch_bounds__(256) void find_bin(
    const unsigned* __restrict__ ghist, unsigned* __restrict__ binIdx,
    unsigned* __restrict__ kRem)
{
    __shared__ unsigned bins[2048];
    __shared__ unsigned csum[256];
    const int bz  = blockIdx.x;
    const int tid = threadIdx.x;
    for (int i = tid; i < 2048; i += 256) bins[i] = ghist[bz * 2048 + i];
    __syncthreads();
    unsigned s = 0;
    #pragma unroll
    for (int j = 0; j < 8; ++j) s += bins[tid * 8 + j];
    csum[tid] = s;
    __syncthreads();
    if (tid == 0) {
        unsigned cum = 0;
        int t;
        for (t = 255; t >= 0; --t) {
            if (cum + csum[t] >= K_TOP) break;
            cum += csum[t];
        }
        for (int bin = t * 8 + 7; bin >= t * 8; --bin) {
            unsigned h = bins[bin];
            if (cum + h >= K_TOP) { binIdx[bz] = (unsigned)bin; kRem[bz] = K_TOP - cum; break; }
            cum += h;
        }
    }
}

// K4: gather cutoff-bin keys; LDS compaction, one global atomic per block.
__global__ __launch_bounds__(256) void collect(
    const float* __restrict__ scores, const unsigned* __restrict__ binIdx,
    unsigned* __restrict__ cand, unsigned* __restrict__ candCnt)
{
    __shared__ unsigned buf[CAP];
    __shared__ unsigned lcnt;
    __shared__ unsigned gbase;
    const int bz  = blockIdx.x >> 4;
    const int seg = blockIdx.x & 15;
    const int tid = threadIdx.x;
    if (tid == 0) lcnt = 0u;
    __syncthreads();
    const unsigned bi = binIdx[bz];
    const float4* p = (const float4*)(scores + (size_t)bz * N_ * S_) + (size_t)seg * 4096;
    for (int i = tid; i < 4096; i += 256) {
        float4 v = p[i];
        unsigned u;
        u = fkey(v.x); if ((u >> 21) == bi) { unsigned qq = atomicAdd(&lcnt, 1u); if (qq < CAP) buf[qq] = u; }
        u = fkey(v.y); if ((u >> 21) == bi) { unsigned qq = atomicAdd(&lcnt, 1u); if (qq < CAP) buf[qq] = u; }
        u = fkey(v.z); if ((u >> 21) == bi) { unsigned qq = atomicAdd(&lcnt, 1u); if (qq < CAP) buf[qq] = u; }
        u = fkey(v.w); if ((u >> 21) == bi) { unsigned qq = atomicAdd(&lcnt, 1u); if (qq < CAP) buf[qq] = u; }
    }
    __syncthreads();
    unsigned c = min(lcnt, (unsigned)CAP);
    if (tid == 0 && c) gbase = atomicAdd(&candCnt[bz], c);
    __syncthreads();
    for (unsigned i = tid; i < c; i += 256) {
        unsigned pos = gbase + i;
        if (pos < CAP) cand[(size_t)bz * CAP + pos] = buf[i];
    }
}

// K5: exact select of kRem-th largest among candidates (radix over low 21 bits)
__global__ __launch_bounds__(256) void exact_select(
    const unsigned* __restrict__ cand, const unsigned* __restrict__ candCnt,
    const unsigned* __restrict__ binIdx, const unsigned* __restrict__ kRem,
    unsigned* __restrict__ Tkey)
{
    __shared__ unsigned list[CAP];
    __shared__ unsigned h[128];
    __shared__ unsigned sh_pref;
    __shared__ int sh_k;
    const int bz  = blockIdx.x;
    const int tid = threadIdx.x;
    int cnt = (int)min(candCnt[bz], (unsigned)CAP);
    for (int i = tid; i < cnt; i += 256) list[i] = cand[(size_t)bz * CAP + i];
    if (tid == 0) { sh_pref = 0u; sh_k = (int)kRem[bz]; }
    __syncthreads();

    #pragma unroll
    for (int r = 0; r < 3; ++r) {
        const int shift = 14 - 7 * r;
        for (int i = tid; i < 128; i += 256) h[i] = 0u;
        __syncthreads();
        const unsigned pref = sh_pref;
        for (int i = tid; i < cnt; i += 256) {
            unsigned u = list[i] & 0x1FFFFFu;
            if ((u >> (shift + 7)) == pref) atomicAdd(&h[(u >> shift) & 127u], 1u);
        }
        __syncthreads();
        if (tid == 0) {
            unsigned cum = 0;
            for (int v = 127; v >= 0; --v) {
                unsigned hh = h[v];
                if (cum + hh >= (unsigned)sh_k) { sh_pref = (pref << 7) | (unsigned)v; sh_k -= (int)cum; break; }
                cum += hh;
            }
        }
        __syncthreads();
    }
    if (tid == 0) Tkey[bz] = (binIdx[bz] << 21) | sh_pref;
}

// K6: per-batch score from 128 rowmax keys
__global__ __launch_bounds__(128) void batch_score(
    const unsigned* __restrict__ rowmaxKey, const unsigned* __restrict__ Tkey,
    float* __restrict__ sc, int b0)
{
    __shared__ float s_sum[2], s_cnt[2];
    const int bz = blockIdx.x;
    const unsigned T = Tkey[bz];
    const int n = threadIdx.x;
    unsigned km = rowmaxKey[bz * N_ + n];
    bool inc = (km >= T);
    float v = inc ? fmaxf(unkey(km), 0.f) : 0.f;
    float c = inc ? 1.f : 0.f;
    #pragma unroll
    for (int off = 32; off > 0; off >>= 1) {
        v += __shfl_xor(v, off, 64);
        c += __shfl_xor(c, off, 64);
    }
    const int w = n >> 6;
    if ((n & 63) == 0) { s_sum[w] = v; s_cnt[w] = c; }
    __syncthreads();
    if (n == 0) {
        float Sv = s_sum[0] + s_sum[1];
        float Cv = s_cnt[0] + s_cnt[1];
        sc[b0 + bz] = Sv / fmaxf(Cv, 0.001f);
    }
}

// K7: loss = mean_b softplus(neg - pos)
__global__ __launch_bounds__(64) void final_loss(
    const float* __restrict__ sc, float* __restrict__ out)
{
    int b = threadIdx.x;
    float x = sc[B_ + b] - sc[b];
    float sp = (x > 20.f) ? x : log1pf(expf(x));
    #pragma unroll
    for (int o = 32; o > 0; o >>= 1) sp += __shfl_xor(sp, o, 64);
    if (b == 0) out[0] = sp * (1.f / B_);
}

extern "C" void kernel_launch(void* const* d_in, const int* in_sizes, int n_in,
                              void* d_out, int out_size, void* d_ws, size_t ws_size,
                              hipStream_t stream) {
    const float* q    = (const float*)d_in[0];
    const float* dpos = (const float*)d_in[1];
    const float* dneg = (const float*)d_in[2];
    float* out = (float*)d_out;
    char* ws = (char*)d_ws;

    const size_t per_batch = (size_t)N_ * S_ * 4
                           + (2048 + N_ + 1) * 4
                           + (size_t)CAP * 4
                           + 12;
    const size_t fixed = 2 * B_ * sizeof(float) + 4096;
    size_t avail = (ws_size > fixed) ? (ws_size - fixed) : 0;
    int Bc = (int)(avail / per_batch);
    if (Bc > B_) Bc = B_;
    if (Bc < 1) Bc = 1;

    const int zwords = Bc * (2048 + N_ + 1);

    char* p = ws;
    float*    sc      = (float*)p; p += ((2 * B_ * 4 + 63) / 64) * 64;
    unsigned* ghist   = (unsigned*)p;
    unsigned* rowmax  = ghist + (size_t)Bc * 2048;
    unsigned* candCnt = rowmax + (size_t)Bc * N_;
    p += ((size_t)zwords * 4 + 63) / 64 * 64;
    float*    scores  = (float*)p;    p += (size_t)Bc * N_ * S_ * 4;
    unsigned* cand    = (unsigned*)p; p += (size_t)Bc * CAP * 4;
    unsigned* binIdx  = (unsigned*)p; p += (size_t)Bc * 4;
    unsigned* kRem    = (unsigned*)p; p += (size_t)Bc * 4;
    unsigned* Tkey    = (unsigned*)p; p += (size_t)Bc * 4;

    for (int c = 0; c < 2; ++c) {
        const float* docs = (c == 0) ? dpos : dneg;
        for (int b0 = 0; b0 < B_; b0 += Bc) {
            int nb = (B_ - b0 < Bc) ? (B_ - b0) : Bc;
            zero_ws<<<(zwords + 255) / 256, 256, 0, stream>>>(ghist, zwords);
            gemm_fused<<<dim3(S_ / 128, 1, nb), 256, 0, stream>>>(q, docs, scores, rowmax, ghist, b0);
            find_bin<<<nb, 256, 0, stream>>>(ghist, binIdx, kRem);
            collect<<<nb * 16, 256, 0, stream>>>(scores, binIdx, cand, candCnt);
            exact_select<<<nb, 256, 0, stream>>>(cand, candCnt, binIdx, kRem, Tkey);
            batch_score<<<nb, 128, 0, stream>>>(rowmax, Tkey, sc + c * B_, b0);
        }
    }
    final_loss<<<1, 64, 0, stream>>>(sc, out);
}

// Round 5
// 299.985 us; speedup vs baseline: 11.5483x; 1.0017x over previous
//
#include <hip/hip_runtime.h>
#include <math.h>

#define B_     64
#define N_     128
#define S_     2048
#define D_     128
#define K_TOP  128
#define CAPB   1024     // per-block candidate cap
#define SELCAP 8192     // per-batch select list cap

typedef __bf16 bf16x8 __attribute__((ext_vector_type(8)));
typedef float  f32x4  __attribute__((ext_vector_type(4)));

union Frag { uint4 u; bf16x8 b; };

// Monotone mapping: float total order -> unsigned total order
__device__ __forceinline__ unsigned fkey(float x) {
    unsigned u = __float_as_uint(x);
    return (u & 0x80000000u) ? ~u : (u | 0x80000000u);
}
__device__ __forceinline__ float unkey(unsigned k) {
    unsigned u = (k & 0x80000000u) ? (k & 0x7fffffffu) : ~k;
    return __uint_as_float(u);
}

// 8 fp32 -> 8 bf16 hi (truncate) + 8 bf16 lo (exact residual, truncate)
__device__ __forceinline__ void cvt8(float4 a, float4 b, uint4& hi, uint4& lo) {
    float v[8] = {a.x, a.y, a.z, a.w, b.x, b.y, b.z, b.w};
    unsigned h[8], l[8];
    #pragma unroll
    for (int i = 0; i < 8; ++i) {
        unsigned u = __float_as_uint(v[i]);
        h[i] = u >> 16;
        float fh = __uint_as_float(u & 0xFFFF0000u);
        l[i] = __float_as_uint(v[i] - fh) >> 16;   // v - hi exact in fp32
    }
    hi.x = h[0] | (h[1] << 16); hi.y = h[2] | (h[3] << 16);
    hi.z = h[4] | (h[5] << 16); hi.w = h[6] | (h[7] << 16);
    lo.x = l[0] | (l[1] << 16); lo.y = l[2] | (l[3] << 16);
    lo.z = l[4] | (l[5] << 16); lo.w = l[6] | (l[7] << 16);
}

// K0: zero rowmax region
__global__ __launch_bounds__(256) void zero_ws(unsigned* __restrict__ p, int n) {
    int i = blockIdx.x * 256 + threadIdx.x;
    if (i < n) p[i] = 0u;
}

// K1: split-bf16 MFMA GEMM (hi*hi + hi*lo + lo*hi), 128x128 tile, K=128.
// NO score materialization. Epilogues (all from registers):
//   (a) per-row max -> global atomicMax
//   (b) local 2048-bin hist -> local top-128 cutoff bin -> candidate keys
//       (>= cutoff) compacted to per-block global slot.
// blockIdx.z in [0, 2*nb): z < nb -> pos docs, else neg docs.
__global__ __launch_bounds__(256) void gemm_fused(
    const float* __restrict__ q, const float* __restrict__ dpos,
    const float* __restrict__ dneg, int nb, int b0,
    unsigned* __restrict__ rowmaxKey, unsigned* __restrict__ cand,
    unsigned* __restrict__ candCnt)
{
    __shared__ uint4 sh4[2048];   // A_hi[512] | A_lo[512] | B_hi[512] | B_lo[512]
    __shared__ unsigned csum[256];
    __shared__ unsigned sh_lb, sh_lcnt;
    const int z  = blockIdx.z;
    const int bz = (z < nb) ? z : z - nb;
    const float* docs = (z < nb) ? dpos : dneg;
    const int s0 = blockIdx.x * 128;
    const float* qb = q + (size_t)(b0 + bz) * N_ * D_;
    const float* db = docs + (size_t)(b0 + bz) * S_ * D_;

    const int t    = threadIdx.x;
    const int lane = t & 63;
    const int w    = t >> 6;
    const int quad = lane >> 4;
    const int m    = lane & 15;

    f32x4 acc[4][4];
    #pragma unroll
    for (int i = 0; i < 4; ++i)
        #pragma unroll
        for (int j = 0; j < 4; ++j)
            acc[i][j] = f32x4{0.f, 0.f, 0.f, 0.f};

    for (int k0 = 0; k0 < D_; k0 += 32) {
        #pragma unroll
        for (int p = 0; p < 2; ++p) {
            int ci  = t + p * 256;                     // chunk 0..511
            int row = ((ci >> 6) << 4) | (ci & 15);    // I*16 + m
            int kk  = k0 + (((ci >> 4) & 3) << 3);     // quad*8
            const float* ga = qb + (size_t)row * D_ + kk;
            float4 a0 = *(const float4*)ga;
            float4 a1 = *(const float4*)(ga + 4);
            uint4 hi, lo;
            cvt8(a0, a1, hi, lo);
            sh4[ci] = hi; sh4[512 + ci] = lo;
            const float* gb = db + (size_t)(s0 + row) * D_ + kk;
            float4 b0v = *(const float4*)gb;
            float4 b1v = *(const float4*)(gb + 4);
            cvt8(b0v, b1v, hi, lo);
            sh4[1024 + ci] = hi; sh4[1536 + ci] = lo;
        }
        __syncthreads();

        Frag ah[4], al[4], bh[4], bl[4];
        #pragma unroll
        for (int i = 0; i < 4; ++i) {
            int I = ((w >> 1) << 2) + i;
            ah[i].u = sh4[I * 64 + lane];
            al[i].u = sh4[512 + I * 64 + lane];
            int J = ((w & 1) << 2) + i;
            bh[i].u = sh4[1024 + J * 64 + lane];
            bl[i].u = sh4[1536 + J * 64 + lane];
        }
        #pragma unroll
        for (int i = 0; i < 4; ++i)
            #pragma unroll
            for (int j = 0; j < 4; ++j) {
                acc[i][j] = __builtin_amdgcn_mfma_f32_16x16x32_bf16(ah[i].b, bh[j].b, acc[i][j], 0, 0, 0);
                acc[i][j] = __builtin_amdgcn_mfma_f32_16x16x32_bf16(ah[i].b, bl[j].b, acc[i][j], 0, 0, 0);
                acc[i][j] = __builtin_amdgcn_mfma_f32_16x16x32_bf16(al[i].b, bh[j].b, acc[i][j], 0, 0, 0);
            }
        __syncthreads();
    }

    // Epilogue (a): per-row max. C/D layout: col = lane&15, row = quad*4 + reg.
    #pragma unroll
    for (int i = 0; i < 4; ++i) {
        int I = ((w >> 1) << 2) + i;
        #pragma unroll
        for (int r = 0; r < 4; ++r) {
            int row = (I << 4) + (quad << 2) + r;
            unsigned km = fkey(acc[i][0][r]);
            km = max(km, fkey(acc[i][1][r]));
            km = max(km, fkey(acc[i][2][r]));
            km = max(km, fkey(acc[i][3][r]));
            #pragma unroll
            for (int off = 1; off < 16; off <<= 1)
                km = max(km, (unsigned)__shfl_xor((int)km, off, 64));
            if (m == 0) atomicMax(&rowmaxKey[z * N_ + row], km);
        }
    }

    // Epilogue (b): local 2048-bin hist (4-way replicated, reuses sh4).
    __syncthreads();
    unsigned* shist = (unsigned*)sh4;                 // 8192 words
    for (int i = t; i < 8192; i += 256) shist[i] = 0u;
    __syncthreads();
    const unsigned rep = t & 3;
    #pragma unroll
    for (int i = 0; i < 4; ++i)
        #pragma unroll
        for (int j = 0; j < 4; ++j)
            #pragma unroll
            for (int r = 0; r < 4; ++r)
                atomicAdd(&shist[((fkey(acc[i][j][r]) >> 21) << 2) | rep], 1u);
    __syncthreads();
    // chunk sums: thread t covers bins [t*8, t*8+8)
    unsigned s = 0;
    #pragma unroll
    for (int j = 0; j < 8; ++j) {
        int bin = t * 8 + j;
        s += shist[bin * 4] + shist[bin * 4 + 1] + shist[bin * 4 + 2] + shist[bin * 4 + 3];
    }
    csum[t] = s;
    __syncthreads();
    if (t == 0) {
        unsigned cum = 0; int tt;
        for (tt = 255; tt >= 0; --tt) {
            if (cum + csum[tt] >= K_TOP) break;
            cum += csum[tt];
        }
        if (tt < 0) tt = 0;
        unsigned lb = (unsigned)(tt * 8);
        for (int bin = tt * 8 + 7; bin >= tt * 8; --bin) {
            unsigned hh = shist[bin * 4] + shist[bin * 4 + 1] + shist[bin * 4 + 2] + shist[bin * 4 + 3];
            if (cum + hh >= K_TOP) { lb = (unsigned)bin; break; }
            cum += hh;
        }
        sh_lb = lb;
        sh_lcnt = 0u;
    }
    __syncthreads();
    const unsigned lb = sh_lb;
    unsigned* buf = (unsigned*)sh4;                   // hist dead; reuse as buffer
    #pragma unroll
    for (int i = 0; i < 4; ++i)
        #pragma unroll
        for (int j = 0; j < 4; ++j)
            #pragma unroll
            for (int r = 0; r < 4; ++r) {
                unsigned u = fkey(acc[i][j][r]);
                if ((u >> 21) >= lb) {
                    unsigned idx = atomicAdd(&sh_lcnt, 1u);
                    if (idx < CAPB) buf[idx] = u;
                }
            }
    __syncthreads();
    unsigned c = min(sh_lcnt, (unsigned)CAPB);
    const int slot = z * 16 + blockIdx.x;
    for (unsigned i = t; i < c; i += 256) cand[(size_t)slot * CAPB + i] = buf[i];
    if (t == 0) candCnt[slot] = c;
}

// K2: per (batch, side): exact 128th-largest key over block candidates
// (4 rounds of radix-256 over full 32-bit key), then score from rowmax.
__global__ __launch_bounds__(256) void select_score(
    const unsigned* __restrict__ cand, const unsigned* __restrict__ candCnt,
    const unsigned* __restrict__ rowmaxKey, float* __restrict__ sc,
    int nb, int b0)
{
    __shared__ unsigned list[SELCAP];
    __shared__ unsigned h[256];
    __shared__ unsigned offs[17];
    __shared__ unsigned sh_pref;
    __shared__ int sh_k;
    __shared__ float s_sum[4], s_cnt[4];
    const int z   = blockIdx.x;            // 0..2nb-1
    const int tid = threadIdx.x;

    if (tid == 0) {
        unsigned o = 0; offs[0] = 0;
        for (int s = 0; s < 16; ++s) {
            o += candCnt[z * 16 + s];
            if (o > SELCAP) o = SELCAP;
            offs[s + 1] = o;
        }
        sh_pref = 0u; sh_k = K_TOP;
    }
    __syncthreads();
    for (int s = 0; s < 16; ++s) {
        unsigned base = offs[s], cnt = offs[s + 1] - offs[s];
        const unsigned* src = cand + (size_t)(z * 16 + s) * CAPB;
        for (unsigned i = tid; i < cnt; i += 256) list[base + i] = src[i];
    }
    const int total = (int)offs[16];
    __syncthreads();

    for (int r = 0; r < 4; ++r) {
        const int shift = 24 - 8 * r;
        h[tid] = 0u;
        __syncthreads();
        const unsigned pref = sh_pref;
        for (int i = tid; i < total; i += 256) {
            unsigned u = list[i];
            bool ok = (r == 0) || ((u >> (shift + 8)) == (pref >> (shift + 8)));
            if (ok) atomicAdd(&h[(u >> shift) & 255u], 1u);
        }
        __syncthreads();
        if (tid == 0) {
            unsigned cum = 0;
            for (int v = 255; v >= 0; --v) {
                unsigned hh = h[v];
                if (cum + hh >= (unsigned)sh_k) {
                    sh_pref = pref | ((unsigned)v << shift);
                    sh_k -= (int)cum;
                    break;
                }
                cum += hh;
            }
        }
        __syncthreads();
    }
    const unsigned T = sh_pref;

    // score from 128 rowmax keys
    float v = 0.f, c = 0.f;
    if (tid < N_) {
        unsigned km = rowmaxKey[z * N_ + tid];
        if (km >= T) { v = fmaxf(unkey(km), 0.f); c = 1.f; }
    }
    #pragma unroll
    for (int off = 32; off > 0; off >>= 1) {
        v += __shfl_xor(v, off, 64);
        c += __shfl_xor(c, off, 64);
    }
    const int w = tid >> 6;
    if ((tid & 63) == 0) { s_sum[w] = v; s_cnt[w] = c; }
    __syncthreads();
    if (tid == 0) {
        float Sv = s_sum[0] + s_sum[1] + s_sum[2] + s_sum[3];
        float Cv = s_cnt[0] + s_cnt[1] + s_cnt[2] + s_cnt[3];
        int b = b0 + ((z < nb) ? z : z - nb);
        int side = (z < nb) ? 0 : 1;
        sc[side * B_ + b] = Sv / fmaxf(Cv, 0.001f);
    }
}

// K3: loss = mean_b softplus(neg - pos)
__global__ __launch_bounds__(64) void final_loss(
    const float* __restrict__ sc, float* __restrict__ out)
{
    int b = threadIdx.x;
    float x = sc[B_ + b] - sc[b];
    float sp = (x > 20.f) ? x : log1pf(expf(x));
    #pragma unroll
    for (int o = 32; o > 0; o >>= 1) sp += __shfl_xor(sp, o, 64);
    if (b == 0) out[0] = sp * (1.f / B_);
}

extern "C" void kernel_launch(void* const* d_in, const int* in_sizes, int n_in,
                              void* d_out, int out_size, void* d_ws, size_t ws_size,
                              hipStream_t stream) {
    const float* q    = (const float*)d_in[0];
    const float* dpos = (const float*)d_in[1];
    const float* dneg = (const float*)d_in[2];
    float* out = (float*)d_out;
    char* ws = (char*)d_ws;

    // per-batch bytes (x2 sides): rowmax 128 + candCnt 16 + cand 16*CAPB words
    const size_t per_batch = 2ull * (N_ + 16 + 16 * CAPB) * 4;
    const size_t fixed = 2 * B_ * sizeof(float) + 256;
    size_t avail = (ws_size > fixed) ? (ws_size - fixed) : 0;
    int Bc = (int)(avail / per_batch);
    if (Bc > B_) Bc = B_;
    if (Bc < 1) Bc = 1;

    char* p = ws;
    float*    sc      = (float*)p; p += ((2 * B_ * 4 + 255) / 256) * 256;
    unsigned* rowmax  = (unsigned*)p; p += (size_t)2 * Bc * N_ * 4;
    unsigned* candCnt = (unsigned*)p; p += (size_t)2 * Bc * 16 * 4;
    unsigned* cand    = (unsigned*)p; p += (size_t)2 * Bc * 16 * CAPB * 4;

    for (int b0 = 0; b0 < B_; b0 += Bc) {
        int nb = (B_ - b0 < Bc) ? (B_ - b0) : Bc;
        zero_ws<<<(2 * nb * N_ + 255) / 256, 256, 0, stream>>>(rowmax, 2 * nb * N_);
        gemm_fused<<<dim3(S_ / 128, 1, 2 * nb), 256, 0, stream>>>(
            q, dpos, dneg, nb, b0, rowmax, cand, candCnt);
        select_score<<<2 * nb, 256, 0, stream>>>(cand, candCnt, rowmax, sc, nb, b0);
    }
    final_loss<<<1, 64, 0, stream>>>(sc, out);
}

// Round 6
// 201.784 us; speedup vs baseline: 17.1683x; 1.4867x over previous
//
#include <hip/hip_runtime.h>
#include <math.h>

#define B_     64
#define N_     128
#define S_     2048
#define D_     128
#define K_TOP  128
#define CAPB   1024     // per-block candidate cap
#define SELCAP 8192     // per-(batch,side) select list cap

typedef _Float16 f16x8 __attribute__((ext_vector_type(8)));
typedef float    f32x4 __attribute__((ext_vector_type(4)));

union Frag { uint4 u; f16x8 h; };

// Monotone mapping: float total order -> unsigned total order
__device__ __forceinline__ unsigned fkey(float x) {
    unsigned u = __float_as_uint(x);
    return (u & 0x80000000u) ? ~u : (u | 0x80000000u);
}
__device__ __forceinline__ float unkey(unsigned k) {
    unsigned u = (k & 0x80000000u) ? (k & 0x7fffffffu) : ~k;
    return __uint_as_float(u);
}

// 8 fp32 -> 8 fp16 (RNE) packed into uint4
__device__ __forceinline__ uint4 cvt8h(float4 a, float4 b) {
    union { _Float16 h[8]; uint4 u; } r;
    r.h[0] = (_Float16)a.x; r.h[1] = (_Float16)a.y;
    r.h[2] = (_Float16)a.z; r.h[3] = (_Float16)a.w;
    r.h[4] = (_Float16)b.x; r.h[5] = (_Float16)b.y;
    r.h[6] = (_Float16)b.z; r.h[7] = (_Float16)b.w;
    return r.u;
}

// K1: fp16 single-pass MFMA GEMM, 128x128 tile, BK=64 (2 iters).
// Epilogues in-register: per-row max (LDS-combined, plain store) and
// local top-128 candidate extraction (2048-bin hist + PARALLEL suffix scan).
// All scratch aliased into one 32 KiB LDS buffer.
__global__ __launch_bounds__(256) void gemm_fused(
    const float* __restrict__ q, const float* __restrict__ dpos,
    const float* __restrict__ dneg, int nb, int b0,
    unsigned* __restrict__ rowmaxLocal,   // [2nb*16*N_]
    unsigned* __restrict__ cand,          // [2nb*16*CAPB]
    unsigned* __restrict__ candCnt)       // [2nb*16]
{
    __shared__ uint4 sh4[2048];           // exactly 32 KiB
    const int z  = blockIdx.z;
    const int bz = (z < nb) ? z : z - nb;
    const float* docs = (z < nb) ? dpos : dneg;
    const int bx = blockIdx.x;
    const int s0 = bx * 128;
    const float* qb = q + (size_t)(b0 + bz) * N_ * D_;
    const float* db = docs + (size_t)(b0 + bz) * S_ * D_;

    const int t    = threadIdx.x;
    const int lane = t & 63;
    const int w    = t >> 6;
    const int quad = lane >> 4;
    const int m    = lane & 15;
    const int Ibase = (w >> 1) << 2;
    const int Jbase = (w & 1) << 2;

    f32x4 acc[4][4];
    #pragma unroll
    for (int i = 0; i < 4; ++i)
        #pragma unroll
        for (int j = 0; j < 4; ++j)
            acc[i][j] = f32x4{0.f, 0.f, 0.f, 0.f};

    for (int k0 = 0; k0 < D_; k0 += 64) {
        // stage A[1024 chunks] | B[1024 chunks]; chunk ci = I*128 + ks*64 + quad*16 + m
        // holds row I*16+m, k-octet (ks*4+quad) -> both write and frag-read are
        // lane-consecutive 16B (conflict-free).
        #pragma unroll
        for (int p = 0; p < 4; ++p) {
            int ci  = t + p * 256;
            int row = ((ci >> 7) << 4) | (ci & 15);
            int kf  = k0 + (((ci >> 4) & 7) << 3);
            const float* ga = qb + (size_t)row * D_ + kf;
            sh4[ci] = cvt8h(*(const float4*)ga, *(const float4*)(ga + 4));
            const float* gb = db + (size_t)(s0 + row) * D_ + kf;
            sh4[1024 + ci] = cvt8h(*(const float4*)gb, *(const float4*)(gb + 4));
        }
        __syncthreads();
        #pragma unroll
        for (int ks = 0; ks < 2; ++ks) {
            Frag af[4], bf[4];
            #pragma unroll
            for (int i = 0; i < 4; ++i) {
                af[i].u = sh4[(Ibase + i) * 128 + ks * 64 + lane];
                bf[i].u = sh4[1024 + (Jbase + i) * 128 + ks * 64 + lane];
            }
            #pragma unroll
            for (int i = 0; i < 4; ++i)
                #pragma unroll
                for (int j = 0; j < 4; ++j)
                    acc[i][j] = __builtin_amdgcn_mfma_f32_16x16x32_f16(
                        af[i].h, bf[j].h, acc[i][j], 0, 0, 0);
        }
        __syncthreads();
    }

    // ---- epilogue scratch, aliased into sh4 (words) ----
    unsigned* shist = (unsigned*)sh4;       // [0,4096): 2048 bins x 2 replicas
    unsigned* scanS = shist + 4096;         // [4096,4352): 256-entry scan
    unsigned* buf   = shist + 4352;         // [4352,5376): candidate buffer
    unsigned* rmx   = shist + 5376;         // [5376,5504): 128 row maxima
    unsigned* ctrl  = shist + 5504;         // [5504]=lb, [5505]=lcnt

    for (int i = t; i < 4096; i += 256) shist[i] = 0u;
    if (t < 128) rmx[t] = 0u;
    if (t == 0) ctrl[1] = 0u;
    __syncthreads();

    // per-row max (C/D layout: col = lane&15, row = quad*4 + reg) + histogram
    const unsigned rep = t & 1;
    #pragma unroll
    for (int i = 0; i < 4; ++i) {
        #pragma unroll
        for (int r = 0; r < 4; ++r) {
            int row = ((Ibase + i) << 4) + (quad << 2) + r;
            unsigned km = max(max(fkey(acc[i][0][r]), fkey(acc[i][1][r])),
                              max(fkey(acc[i][2][r]), fkey(acc[i][3][r])));
            #pragma unroll
            for (int off = 1; off < 16; off <<= 1)
                km = max(km, (unsigned)__shfl_xor((int)km, off, 64));
            if (m == 0) atomicMax(&rmx[row], km);
            #pragma unroll
            for (int j = 0; j < 4; ++j)
                atomicAdd(&shist[((fkey(acc[i][j][r]) >> 21) << 1) | rep], 1u);
        }
    }
    __syncthreads();

    const int slot = z * 16 + bx;
    if (t < 128) rowmaxLocal[(size_t)slot * N_ + t] = rmx[t];

    // chunk sums: thread t covers bins [8t, 8t+8)
    {
        unsigned s = 0;
        #pragma unroll
        for (int j = 0; j < 8; ++j) {
            int bin = t * 8 + j;
            s += shist[bin * 2] + shist[bin * 2 + 1];
        }
        scanS[t] = s;
    }
    __syncthreads();
    // in-place suffix scan (Hillis-Steele, 8 steps)
    #pragma unroll
    for (int d = 1; d < 256; d <<= 1) {
        unsigned v = scanS[t] + ((t + d < 256) ? scanS[t + d] : 0u);
        __syncthreads();
        scanS[t] = v;
        __syncthreads();
    }
    // unique crossing chunk: suffix[t] >= K > suffix[t+1]
    {
        unsigned Sme = scanS[t];
        unsigned Snx = (t == 255) ? 0u : scanS[t + 1];
        if (Sme >= K_TOP && Snx < K_TOP) {
            unsigned cum = Snx;
            unsigned lb = (unsigned)(t * 8);
            for (int bin = t * 8 + 7; bin >= t * 8; --bin) {
                unsigned hh = shist[bin * 2] + shist[bin * 2 + 1];
                if (cum + hh >= K_TOP) { lb = (unsigned)bin; break; }
                cum += hh;
            }
            ctrl[0] = lb;
        }
    }
    __syncthreads();
    const unsigned lb = ctrl[0];

    // compact all keys with bin >= lb (superset of block top-128)
    #pragma unroll
    for (int i = 0; i < 4; ++i)
        #pragma unroll
        for (int j = 0; j < 4; ++j)
            #pragma unroll
            for (int r = 0; r < 4; ++r) {
                unsigned u = fkey(acc[i][j][r]);
                if ((u >> 21) >= lb) {
                    unsigned idx = atomicAdd(&ctrl[1], 1u);
                    if (idx < CAPB) buf[idx] = u;
                }
            }
    __syncthreads();
    unsigned c = min(ctrl[1], (unsigned)CAPB);
    for (unsigned i = t; i < c; i += 256) cand[(size_t)slot * CAPB + i] = buf[i];
    if (t == 0) candCnt[slot] = c;
}

// K2: per (batch,side): exact 128th-largest key over the 16 blocks' candidates
// (4 radix-256 rounds, parallel suffix-scan bin-find), then score from rowmax.
__global__ __launch_bounds__(256) void select_score(
    const unsigned* __restrict__ cand, const unsigned* __restrict__ candCnt,
    const unsigned* __restrict__ rowmaxLocal, float* __restrict__ sc,
    int nb, int b0)
{
    __shared__ unsigned list[SELCAP];
    __shared__ unsigned h[256];
    __shared__ unsigned cnts[16];
    __shared__ unsigned offs[17];
    __shared__ unsigned sh_pref;
    __shared__ int sh_k;
    __shared__ float s_sum[4], s_cnt[4];
    const int z   = blockIdx.x;
    const int tid = threadIdx.x;

    if (tid < 16) cnts[tid] = candCnt[z * 16 + tid];
    if (tid == 0) { sh_pref = 0u; sh_k = K_TOP; }
    __syncthreads();
    if (tid <= 16) {               // each thread computes its own prefix (parallel)
        unsigned o = 0;
        for (int s = 0; s < tid; ++s) o += cnts[s];
        offs[tid] = min(o, (unsigned)SELCAP);
    }
    __syncthreads();
    for (int s = 0; s < 16; ++s) {
        unsigned base = offs[s], cnt = min(offs[s + 1], (unsigned)SELCAP) - base;
        const unsigned* src = cand + (size_t)(z * 16 + s) * CAPB;
        for (unsigned i = tid; i < cnt; i += 256) list[base + i] = src[i];
    }
    const int total = (int)offs[16];

    // per-row max across the 16 blocks (kept in register; tid<128 owns row tid)
    unsigned myrm = 0u;
    if (tid < N_) {
        #pragma unroll
        for (int s = 0; s < 16; ++s)
            myrm = max(myrm, rowmaxLocal[(size_t)(z * 16 + s) * N_ + tid]);
    }
    __syncthreads();

    for (int r = 0; r < 4; ++r) {
        const int shift = 24 - 8 * r;
        h[tid] = 0u;
        __syncthreads();
        const unsigned pref = sh_pref;
        const int k = sh_k;
        for (int i = tid; i < total; i += 256) {
            unsigned u = list[i];
            bool ok = (r == 0) || ((u >> (shift + 8)) == (pref >> (shift + 8)));
            if (ok) atomicAdd(&h[(u >> shift) & 255u], 1u);
        }
        __syncthreads();
        #pragma unroll
        for (int d = 1; d < 256; d <<= 1) {
            unsigned v = h[tid] + ((tid + d < 256) ? h[tid + d] : 0u);
            __syncthreads();
            h[tid] = v;
            __syncthreads();
        }
        unsigned Sme = h[tid];
        unsigned Snx = (tid == 255) ? 0u : h[tid + 1];
        if (Sme >= (unsigned)k && Snx < (unsigned)k) {
            sh_pref = pref | ((unsigned)tid << shift);
            sh_k    = k - (int)Snx;
        }
        __syncthreads();
    }
    const unsigned T = sh_pref;

    // score from 128 row maxima
    float v = 0.f, c = 0.f;
    if (tid < N_ && myrm >= T) { v = fmaxf(unkey(myrm), 0.f); c = 1.f; }
    #pragma unroll
    for (int off = 32; off > 0; off >>= 1) {
        v += __shfl_xor(v, off, 64);
        c += __shfl_xor(c, off, 64);
    }
    const int w = tid >> 6;
    if ((tid & 63) == 0) { s_sum[w] = v; s_cnt[w] = c; }
    __syncthreads();
    if (tid == 0) {
        float Sv = s_sum[0] + s_sum[1] + s_sum[2] + s_sum[3];
        float Cv = s_cnt[0] + s_cnt[1] + s_cnt[2] + s_cnt[3];
        int b = b0 + ((z < nb) ? z : z - nb);
        int side = (z < nb) ? 0 : 1;
        sc[side * B_ + b] = Sv / fmaxf(Cv, 0.001f);
    }
}

// K3: loss = mean_b softplus(neg - pos)
__global__ __launch_bounds__(64) void final_loss(
    const float* __restrict__ sc, float* __restrict__ out)
{
    int b = threadIdx.x;
    float x = sc[B_ + b] - sc[b];
    float sp = (x > 20.f) ? x : log1pf(expf(x));
    #pragma unroll
    for (int o = 32; o > 0; o >>= 1) sp += __shfl_xor(sp, o, 64);
    if (b == 0) out[0] = sp * (1.f / B_);
}

extern "C" void kernel_launch(void* const* d_in, const int* in_sizes, int n_in,
                              void* d_out, int out_size, void* d_ws, size_t ws_size,
                              hipStream_t stream) {
    const float* q    = (const float*)d_in[0];
    const float* dpos = (const float*)d_in[1];
    const float* dneg = (const float*)d_in[2];
    float* out = (float*)d_out;
    char* ws = (char*)d_ws;

    // per-batch bytes (x2 sides): rowmaxLocal 16*128 + cand 16*CAPB + candCnt 16
    const size_t per_batch = 2ull * (16 * N_ + 16 * CAPB + 16) * 4;
    const size_t fixed = 2 * B_ * sizeof(float) + 256;
    size_t avail = (ws_size > fixed) ? (ws_size - fixed) : 0;
    int Bc = (int)(avail / per_batch);
    if (Bc > B_) Bc = B_;
    if (Bc < 1) Bc = 1;

    char* p = ws;
    float*    sc          = (float*)p;    p += ((2 * B_ * 4 + 255) / 256) * 256;
    unsigned* rowmaxLocal = (unsigned*)p; p += (size_t)2 * Bc * 16 * N_ * 4;
    unsigned* candCnt     = (unsigned*)p; p += (size_t)2 * Bc * 16 * 4;
    unsigned* cand        = (unsigned*)p; p += (size_t)2 * Bc * 16 * CAPB * 4;

    for (int b0 = 0; b0 < B_; b0 += Bc) {
        int nb = (B_ - b0 < Bc) ? (B_ - b0) : Bc;
        gemm_fused<<<dim3(S_ / 128, 1, 2 * nb), 256, 0, stream>>>(
            q, dpos, dneg, nb, b0, rowmaxLocal, cand, candCnt);
        select_score<<<2 * nb, 256, 0, stream>>>(
            cand, candCnt, rowmaxLocal, sc, nb, b0);
    }
    final_loss<<<1, 64, 0, stream>>>(sc, out);
}